// Round 7
// baseline (233.033 us; speedup 1.0000x reference)
//
#include <hip/hip_runtime.h>
#include <stdint.h>

#define BATCH 16384
#define SDIM 512
#define ADIM 64
#define XDIM 576      // SDIM + ADIM
#define HDIM 1024
#define NQD 64
#define QED 64

typedef __attribute__((ext_vector_type(8))) short short8;
typedef __attribute__((ext_vector_type(4))) float f32x4;

static __device__ inline unsigned short f2bf(float f) {
  unsigned int u = __float_as_uint(f);
  unsigned int r = (u + 0x7fffu + ((u >> 16) & 1u)) >> 16;
  return (unsigned short)r;
}
static __device__ inline float bf2f(unsigned short u) {
  return __uint_as_float(((unsigned int)u) << 16);
}

static __device__ inline void gload_lds16(const void* g, void* l) {
  __builtin_amdgcn_global_load_lds(
      (const __attribute__((address_space(1))) uint32_t*)g,
      (__attribute__((address_space(3))) uint32_t*)l, 16, 0, 0);
}

#define FENCE() asm volatile("" ::: "memory")

// ---------------- conversion kernels ----------------

__global__ __launch_bounds__(256) void cvt_x(const float* __restrict__ st,
                                             const float* __restrict__ ac,
                                             unsigned short* __restrict__ xb) {
  const int total = BATCH * XDIM / 4;
  for (int i = blockIdx.x * blockDim.x + threadIdx.x; i < total;
       i += gridDim.x * blockDim.x) {
    const int e = i * 4;
    const int b = e / XDIM;
    const int j = e - b * XDIM;
    float4 v;
    if (j < SDIM) v = *(const float4*)(st + (size_t)b * SDIM + j);
    else          v = *(const float4*)(ac + (size_t)b * ADIM + (j - SDIM));
    ushort4 o;
    o.x = f2bf(v.x); o.y = f2bf(v.y); o.z = f2bf(v.z); o.w = f2bf(v.w);
    ((ushort4*)xb)[i] = o;
  }
}

__global__ __launch_bounds__(256) void cvt_w2(const float* __restrict__ s1,
                                              unsigned short* __restrict__ d1, int n1,
                                              const float* __restrict__ s2,
                                              unsigned short* __restrict__ d2, int n2) {
  for (int i = blockIdx.x * blockDim.x + threadIdx.x; i < n1 + n2;
       i += gridDim.x * blockDim.x) {
    const float4 v = (i < n1) ? ((const float4*)s1)[i] : ((const float4*)s2)[i - n1];
    ushort4 o;
    o.x = f2bf(v.x); o.y = f2bf(v.y); o.z = f2bf(v.z); o.w = f2bf(v.w);
    if (i < n1) ((ushort4*)d1)[i] = o; else ((ushort4*)d2)[i - n1] = o;
  }
}

// ---------------- tau embedding head contribution (exact fp32) ----------------

__global__ void qtau_kernel(const float* __restrict__ We1, const float* __restrict__ be1,
                            const float* __restrict__ We2, const float* __restrict__ be2,
                            const float* __restrict__ Wh,  const float* __restrict__ bh,
                            float* __restrict__ qtau) {
  const int c = blockIdx.x >> 6;
  const int nq = blockIdx.x & 63;
  const int q = threadIdx.x;  // 64 threads = 1 wave
  const float tau = (float)nq / 64.0f + 0.0078125f;
  float acc = be2[c * 64 + q];
  for (int e = 0; e < 64; ++e) {
    const float t1 = fmaxf(tau * We1[c * 64 + e] + be1[c * 64 + e], 0.0f);
    acc += t1 * We2[(c * 64 + q) * 64 + e];
  }
  float v = acc * Wh[c * (HDIM + QED) + HDIM + q];
  #pragma unroll
  for (int off = 32; off; off >>= 1) v += __shfl_xor(v, off);
  if (q == 0) qtau[c * 64 + nq] = v + bh[c];
}

// ---------------- 256x256 bf16 GEMM, ring-4 LDS, 3-deep prefetch ----------
// C[M,1024] = A[M,K] * W[1024,K]^T + bias. 8 waves (2M x 4N), BK=32,
// 4 ring buffers (128 KiB). Per K-tile: stage(t+3) -> frag reads of tile t
// -> 32 MFMA -> counted vmcnt (drain only t+1's 4 loads; 12 in flight) ->
// ONE barrier. Ring slot (t+3)&3 was last read at t-1, protected by t-1's
// barrier. Both-sides swizzle slot ^= (row>>1)&3 (2-way = free for 64B rows).

template <int K>
__global__ __launch_bounds__(512, 2) void gemm_ring(const unsigned short* __restrict__ A,
                                                    const unsigned short* __restrict__ W,
                                                    const float* __restrict__ bias,
                                                    unsigned short* __restrict__ C) {
  constexpr int NT = K / 32;
  __shared__ unsigned short As[4][256][32];
  __shared__ unsigned short Bs[4][256][32];

  const int tid  = threadIdx.x;
  const int lane = tid & 63;
  const int wave = tid >> 6;
  const int wm = wave >> 2;   // 0..1 -> rows [wm*128, wm*128+128)
  const int wn = wave & 3;    // 0..3 -> cols [wn*64,  wn*64+64)

  // XCD-bijective swizzle: 256 blocks, 8 XCDs, 32 contiguous logical per XCD,
  // n-fastest so the 4 blocks sharing an A-panel are XCD-co-resident.
  const int bid = (int)blockIdx.x;
  const int logical = (bid & 7) * 32 + (bid >> 3);
  const int mBase = (logical >> 2) * 256;
  const int nBase = (logical & 3) * 256;

  auto stage = [&](int ring, int kt) {
    #pragma unroll
    for (int i = 0; i < 2; ++i) {
      const int flat = i * 512 + tid;
      const int row  = flat >> 2;
      const int ps   = flat & 3;
      const int ls   = ps ^ ((row >> 1) & 3);  // inverse-swizzled source slot
      gload_lds16(A + (size_t)(mBase + row) * K + kt * 32 + ls * 8,
                  &As[ring][0][0] + (size_t)flat * 8);
      gload_lds16(W + (size_t)(nBase + row) * K + kt * 32 + ls * 8,
                  &Bs[ring][0][0] + (size_t)flat * 8);
    }
  };

  f32x4 acc[8][4];
  #pragma unroll
  for (int fm = 0; fm < 8; ++fm)
    #pragma unroll
    for (int fn = 0; fn < 4; ++fn) {
      f32x4 z = {0.f, 0.f, 0.f, 0.f};
      acc[fm][fn] = z;
    }

  // prologue: stage tiles 0,1,2 (12 loads); wait tile0 (drain 4 of 12)
  stage(0, 0);
  if (NT > 1) stage(1, 1);
  if (NT > 2) stage(2, 2);
  FENCE();
  if (NT > 2)      asm volatile("s_waitcnt vmcnt(8)" ::: "memory");
  else if (NT > 1) asm volatile("s_waitcnt vmcnt(4)" ::: "memory");
  else             asm volatile("s_waitcnt vmcnt(0)" ::: "memory");
  __builtin_amdgcn_s_barrier();
  FENCE();

  for (int t = 0; t < NT; ++t) {
    const int ring = t & 3;
    if (t + 3 < NT) stage((t + 3) & 3, t + 3);

    short8 af[8], bf[4];
    #pragma unroll
    for (int fm = 0; fm < 8; ++fm) {
      const int r  = wm * 128 + fm * 16 + (lane & 15);
      const int ps = (lane >> 4) ^ ((r >> 1) & 3);
      af[fm] = *(const short8*)&As[ring][r][ps * 8];
    }
    #pragma unroll
    for (int fn = 0; fn < 4; ++fn) {
      const int r  = wn * 64 + fn * 16 + (lane & 15);
      const int ps = (lane >> 4) ^ ((r >> 1) & 3);
      bf[fn] = *(const short8*)&Bs[ring][r][ps * 8];
    }

    __builtin_amdgcn_s_setprio(1);
    #pragma unroll
    for (int fm = 0; fm < 8; ++fm)
      #pragma unroll
      for (int fn = 0; fn < 4; ++fn)
        acc[fm][fn] = __builtin_amdgcn_mfma_f32_16x16x32_bf16(af[fm], bf[fn],
                                                              acc[fm][fn], 0, 0, 0);
    __builtin_amdgcn_s_setprio(0);

    if (t + 1 < NT) {
      FENCE();
      if (t + 3 < NT)      asm volatile("s_waitcnt vmcnt(8)" ::: "memory");
      else if (t + 2 < NT) asm volatile("s_waitcnt vmcnt(4)" ::: "memory");
      else                 asm volatile("s_waitcnt vmcnt(0)" ::: "memory");
      __builtin_amdgcn_s_barrier();
      FENCE();
    }
  }

  // epilogue: bias add + bf16 round + store
  #pragma unroll
  for (int fm = 0; fm < 8; ++fm) {
    const int r0 = mBase + wm * 128 + fm * 16 + (lane >> 4) * 4;
    #pragma unroll
    for (int fn = 0; fn < 4; ++fn) {
      const int col = nBase + wn * 64 + fn * 16 + (lane & 15);
      const float bv = bias[col];
      #pragma unroll
      for (int j = 0; j < 4; ++j)
        C[(size_t)(r0 + j) * HDIM + col] = f2bf(acc[fm][fn][j] + bv);
    }
  }
}

// ---------------- row LayerNorm + ReLU (+ optional fused head) ----------------

template <bool HEAD>
__global__ __launch_bounds__(256) void ln_head(const unsigned short* __restrict__ X,
                                               const float* __restrict__ g,
                                               const float* __restrict__ bta,
                                               unsigned short* __restrict__ Y,
                                               const float* __restrict__ Wh,
                                               const float* __restrict__ qt,
                                               float* __restrict__ out) {
  const int b = blockIdx.x;
  const int tid = threadIdx.x;
  const int lane = tid & 63;
  const int wave = tid >> 6;
  __shared__ float rs_[4], rq_[4], rp_[4];

  const ushort4 xv = ((const ushort4*)(X + (size_t)b * HDIM))[tid];
  const float x0 = bf2f(xv.x), x1 = bf2f(xv.y), x2 = bf2f(xv.z), x3 = bf2f(xv.w);
  float s = x0 + x1 + x2 + x3;
  float q = x0 * x0 + x1 * x1 + x2 * x2 + x3 * x3;
  #pragma unroll
  for (int off = 32; off; off >>= 1) {
    s += __shfl_xor(s, off);
    q += __shfl_xor(q, off);
  }
  if (lane == 0) { rs_[wave] = s; rq_[wave] = q; }
  __syncthreads();
  s = rs_[0] + rs_[1] + rs_[2] + rs_[3];
  q = rq_[0] + rq_[1] + rq_[2] + rq_[3];
  const float mu = s * (1.0f / 1024.0f);
  const float var = q * (1.0f / 1024.0f) - mu * mu;
  const float rsig = rsqrtf(var + 1e-5f);

  const float4 gv = ((const float4*)g)[tid];
  const float4 bv = ((const float4*)bta)[tid];
  const float y0 = fmaxf((x0 - mu) * rsig * gv.x + bv.x, 0.0f);
  const float y1 = fmaxf((x1 - mu) * rsig * gv.y + bv.y, 0.0f);
  const float y2 = fmaxf((x2 - mu) * rsig * gv.z + bv.z, 0.0f);
  const float y3 = fmaxf((x3 - mu) * rsig * gv.w + bv.w, 0.0f);

  if constexpr (!HEAD) {
    ushort4 o;
    o.x = f2bf(y0); o.y = f2bf(y1); o.z = f2bf(y2); o.w = f2bf(y3);
    ((ushort4*)(Y + (size_t)b * HDIM))[tid] = o;
  } else {
    const float4 wv = ((const float4*)Wh)[tid];
    float p = y0 * wv.x + y1 * wv.y + y2 * wv.z + y3 * wv.w;
    #pragma unroll
    for (int off = 32; off; off >>= 1) p += __shfl_xor(p, off);
    if (lane == 0) rp_[wave] = p;
    __syncthreads();
    if (tid < 64) {
      const float qf = rp_[0] + rp_[1] + rp_[2] + rp_[3];
      out[(size_t)b * NQD + tid] = qf + qt[tid];
    }
  }
}

// ---------------- launch ----------------

extern "C" void kernel_launch(void* const* d_in, const int* in_sizes, int n_in,
                              void* d_out, int out_size, void* d_ws, size_t ws_size,
                              hipStream_t stream) {
  (void)in_sizes; (void)n_in; (void)out_size; (void)ws_size;
  const float* state  = (const float*)d_in[0];
  const float* action = (const float*)d_in[1];
  const float* We1 = (const float*)d_in[2];
  const float* be1 = (const float*)d_in[3];
  const float* We2 = (const float*)d_in[4];
  const float* be2 = (const float*)d_in[5];
  const float* Wf1 = (const float*)d_in[6];
  const float* bW1 = (const float*)d_in[7];
  const float* g1  = (const float*)d_in[8];
  const float* bt1 = (const float*)d_in[9];
  const float* Wf2 = (const float*)d_in[10];
  const float* bW2 = (const float*)d_in[11];
  const float* g2  = (const float*)d_in[12];
  const float* bt2 = (const float*)d_in[13];
  const float* Wh  = (const float*)d_in[14];
  const float* bh  = (const float*)d_in[15];
  float* out = (float*)d_out;

  char* ws = (char*)d_ws;
  unsigned short* xb   = (unsigned short*)(ws);               // BATCH*576 bf16
  unsigned short* w1b  = (unsigned short*)(ws + 18874368);    // 2*1024*576 bf16
  unsigned short* w2b  = (unsigned short*)(ws + 21233664);    // 2*1024*1024 bf16
  float*          qtw  = (float*)(ws + 25427968);             // 2*64 f32
  unsigned short* ha   = (unsigned short*)(ws + 25428480);    // BATCH*1024 bf16
  unsigned short* hb   = (unsigned short*)(ws + 58982912);    // BATCH*1024 bf16

  cvt_x<<<2048, 256, 0, stream>>>(state, action, xb);
  cvt_w2<<<2048, 256, 0, stream>>>(Wf1, w1b, 2 * HDIM * XDIM / 4,
                                   Wf2, w2b, 2 * HDIM * HDIM / 4);
  qtau_kernel<<<128, 64, 0, stream>>>(We1, be1, We2, be2, Wh, bh, qtw);

  for (int c = 0; c < 2; ++c) {
    gemm_ring<XDIM><<<256, 512, 0, stream>>>(
        xb, w1b + (size_t)c * HDIM * XDIM, bW1 + c * HDIM, ha);
    ln_head<false><<<BATCH, 256, 0, stream>>>(
        ha, g1 + c * HDIM, bt1 + c * HDIM, hb, nullptr, nullptr, nullptr);
    gemm_ring<HDIM><<<256, 512, 0, stream>>>(
        hb, w2b + (size_t)c * HDIM * HDIM, bW2 + c * HDIM, ha);
    ln_head<true><<<BATCH, 256, 0, stream>>>(
        ha, g2 + c * HDIM, bt2 + c * HDIM, nullptr,
        Wh + (size_t)c * (HDIM + QED), qtw + c * 64, out + (size_t)c * BATCH * NQD);
  }
}

// Round 8
// 213.507 us; speedup vs baseline: 1.0915x; 1.0915x over previous
//
#include <hip/hip_runtime.h>
#include <stdint.h>

#define BATCH 16384
#define SDIM 512
#define ADIM 64
#define XDIM 576      // SDIM + ADIM
#define HDIM 1024
#define NQD 64
#define QED 64

typedef __attribute__((ext_vector_type(8))) short short8;
typedef __attribute__((ext_vector_type(4))) float f32x4;

static __device__ inline unsigned short f2bf(float f) {
  unsigned int u = __float_as_uint(f);
  unsigned int r = (u + 0x7fffu + ((u >> 16) & 1u)) >> 16;
  return (unsigned short)r;
}
static __device__ inline float bf2f(unsigned short u) {
  return __uint_as_float(((unsigned int)u) << 16);
}

static __device__ inline void gload_lds16(const void* g, void* l) {
  __builtin_amdgcn_global_load_lds(
      (const __attribute__((address_space(1))) uint32_t*)g,
      (__attribute__((address_space(3))) uint32_t*)l, 16, 0, 0);
}

// ---------------- merged conversion kernel ----------------
// covers: x concat+cvt, W_f1 cvt, W_f2 cvt (one dispatch)

__global__ __launch_bounds__(256) void prep(const float* __restrict__ st,
                                            const float* __restrict__ ac,
                                            unsigned short* __restrict__ xb,
                                            const float* __restrict__ w1s,
                                            unsigned short* __restrict__ w1d,
                                            const float* __restrict__ w2s,
                                            unsigned short* __restrict__ w2d) {
  const int nx = BATCH * XDIM / 4;
  const int n1 = 2 * HDIM * XDIM / 4;
  const int n2 = 2 * HDIM * HDIM / 4;
  for (int i = blockIdx.x * blockDim.x + threadIdx.x; i < nx + n1 + n2;
       i += gridDim.x * blockDim.x) {
    float4 v;
    unsigned short* dst;
    int di;
    if (i < nx) {
      const int e = i * 4;
      const int b = e / XDIM;
      const int j = e - b * XDIM;
      if (j < SDIM) v = *(const float4*)(st + (size_t)b * SDIM + j);
      else          v = *(const float4*)(ac + (size_t)b * ADIM + (j - SDIM));
      dst = xb; di = i;
    } else if (i < nx + n1) {
      di = i - nx; v = ((const float4*)w1s)[di]; dst = w1d;
    } else {
      di = i - nx - n1; v = ((const float4*)w2s)[di]; dst = w2d;
    }
    ushort4 o;
    o.x = f2bf(v.x); o.y = f2bf(v.y); o.z = f2bf(v.z); o.w = f2bf(v.w);
    ((ushort4*)dst)[di] = o;
  }
}

// ---------------- tau embedding head contribution (exact fp32) ----------------

__global__ void qtau_kernel(const float* __restrict__ We1, const float* __restrict__ be1,
                            const float* __restrict__ We2, const float* __restrict__ be2,
                            const float* __restrict__ Wh,  const float* __restrict__ bh,
                            float* __restrict__ qtau) {
  const int c = blockIdx.x >> 6;
  const int nq = blockIdx.x & 63;
  const int q = threadIdx.x;  // 64 threads = 1 wave
  const float tau = (float)nq / 64.0f + 0.0078125f;
  float acc = be2[c * 64 + q];
  for (int e = 0; e < 64; ++e) {
    const float t1 = fmaxf(tau * We1[c * 64 + e] + be1[c * 64 + e], 0.0f);
    acc += t1 * We2[(c * 64 + q) * 64 + e];
  }
  float v = acc * Wh[c * (HDIM + QED) + HDIM + q];
  #pragma unroll
  for (int off = 32; off; off >>= 1) v += __shfl_xor(v, off);
  if (q == 0) qtau[c * 64 + nq] = v + bh[c];
}

// ---------------- 256x128 bf16 GEMM, 2 blocks/CU TLP ----------------------
// C[M,1024] = A[M,K] * W[1024,K]^T + bias. 8 waves (4M x 2N), per-wave 64x64
// (acc 64 VGPR). BK=32, 48 KiB LDS double-buffer, <=128 VGPR forced by
// __launch_bounds__(512,4) -> 2 blocks/CU resident; cross-block wave overlap
// hides the barrier drain (m114/m97 mechanism). Grid 512 = exactly 2/CU.
// XCD-bijective swizzle, both-sides slot swizzle (slot ^= (row>>1)&3).

template <int K>
__global__ __launch_bounds__(512, 4) void gemm_mn(const unsigned short* __restrict__ A,
                                                  const unsigned short* __restrict__ W,
                                                  const float* __restrict__ bias,
                                                  unsigned short* __restrict__ C) {
  constexpr int NT = K / 32;
  __shared__ unsigned short As[2][256][32];  // 32 KiB
  __shared__ unsigned short Bs[2][128][32];  // 16 KiB

  const int tid  = threadIdx.x;
  const int lane = tid & 63;
  const int wave = tid >> 6;
  const int wm = wave >> 1;   // 0..3 -> rows [wm*64, wm*64+64)
  const int wn = wave & 1;    // 0..1 -> cols [wn*64, wn*64+64)

  // XCD-bijective swizzle: 512 blocks, 8 XCDs, 64 contiguous logical per XCD,
  // n-fastest so the 8 blocks sharing an A-panel are XCD-co-resident.
  const int bid = (int)blockIdx.x;
  const int logical = (bid & 7) * 64 + (bid >> 3);
  const int mBase = (logical >> 3) * 256;
  const int nBase = (logical & 7) * 128;

  auto stage = [&](int buf, int kt) {
    #pragma unroll
    for (int i = 0; i < 2; ++i) {
      const int flat = i * 512 + tid;
      const int row  = flat >> 2;
      const int ls   = (flat & 3) ^ ((row >> 1) & 3);
      gload_lds16(A + (size_t)(mBase + row) * K + kt * 32 + ls * 8,
                  &As[buf][0][0] + (size_t)flat * 8);
    }
    {
      const int row = tid >> 2;
      const int ls  = (tid & 3) ^ ((row >> 1) & 3);
      gload_lds16(W + (size_t)(nBase + row) * K + kt * 32 + ls * 8,
                  &Bs[buf][0][0] + (size_t)tid * 8);
    }
  };

  f32x4 acc[4][4];
  #pragma unroll
  for (int fm = 0; fm < 4; ++fm)
    #pragma unroll
    for (int fn = 0; fn < 4; ++fn) {
      f32x4 z = {0.f, 0.f, 0.f, 0.f};
      acc[fm][fn] = z;
    }

  stage(0, 0);
  __syncthreads();

  for (int t = 0; t < NT; ++t) {
    const int buf = t & 1;
    if (t + 1 < NT) stage(buf ^ 1, t + 1);

    short8 af[4], bf[4];
    #pragma unroll
    for (int fm = 0; fm < 4; ++fm) {
      const int r  = wm * 64 + fm * 16 + (lane & 15);
      const int ps = (lane >> 4) ^ ((r >> 1) & 3);
      af[fm] = *(const short8*)&As[buf][r][ps * 8];
    }
    #pragma unroll
    for (int fn = 0; fn < 4; ++fn) {
      const int r  = wn * 64 + fn * 16 + (lane & 15);
      const int ps = (lane >> 4) ^ ((r >> 1) & 3);
      bf[fn] = *(const short8*)&Bs[buf][r][ps * 8];
    }

    __builtin_amdgcn_s_setprio(1);
    #pragma unroll
    for (int fm = 0; fm < 4; ++fm)
      #pragma unroll
      for (int fn = 0; fn < 4; ++fn)
        acc[fm][fn] = __builtin_amdgcn_mfma_f32_16x16x32_bf16(af[fm], bf[fn],
                                                              acc[fm][fn], 0, 0, 0);
    __builtin_amdgcn_s_setprio(0);
    __syncthreads();
  }

  // epilogue: bias add + bf16 round + store
  #pragma unroll
  for (int fm = 0; fm < 4; ++fm) {
    const int r0 = mBase + wm * 64 + fm * 16 + (lane >> 4) * 4;
    #pragma unroll
    for (int fn = 0; fn < 4; ++fn) {
      const int col = nBase + wn * 64 + fn * 16 + (lane & 15);
      const float bv = bias[col];
      #pragma unroll
      for (int j = 0; j < 4; ++j)
        C[(size_t)(r0 + j) * HDIM + col] = f2bf(acc[fm][fn][j] + bv);
    }
  }
}

// ---------------- row LayerNorm + ReLU (+ optional fused head) ----------------

template <bool HEAD>
__global__ __launch_bounds__(256) void ln_head(const unsigned short* __restrict__ X,
                                               const float* __restrict__ g,
                                               const float* __restrict__ bta,
                                               unsigned short* __restrict__ Y,
                                               const float* __restrict__ Wh,
                                               const float* __restrict__ qt,
                                               float* __restrict__ out) {
  const int b = blockIdx.x;
  const int tid = threadIdx.x;
  const int lane = tid & 63;
  const int wave = tid >> 6;
  __shared__ float rs_[4], rq_[4], rp_[4];

  const ushort4 xv = ((const ushort4*)(X + (size_t)b * HDIM))[tid];
  const float x0 = bf2f(xv.x), x1 = bf2f(xv.y), x2 = bf2f(xv.z), x3 = bf2f(xv.w);
  float s = x0 + x1 + x2 + x3;
  float q = x0 * x0 + x1 * x1 + x2 * x2 + x3 * x3;
  #pragma unroll
  for (int off = 32; off; off >>= 1) {
    s += __shfl_xor(s, off);
    q += __shfl_xor(q, off);
  }
  if (lane == 0) { rs_[wave] = s; rq_[wave] = q; }
  __syncthreads();
  s = rs_[0] + rs_[1] + rs_[2] + rs_[3];
  q = rq_[0] + rq_[1] + rq_[2] + rq_[3];
  const float mu = s * (1.0f / 1024.0f);
  const float var = q * (1.0f / 1024.0f) - mu * mu;
  const float rsig = rsqrtf(var + 1e-5f);

  const float4 gv = ((const float4*)g)[tid];
  const float4 bv = ((const float4*)bta)[tid];
  const float y0 = fmaxf((x0 - mu) * rsig * gv.x + bv.x, 0.0f);
  const float y1 = fmaxf((x1 - mu) * rsig * gv.y + bv.y, 0.0f);
  const float y2 = fmaxf((x2 - mu) * rsig * gv.z + bv.z, 0.0f);
  const float y3 = fmaxf((x3 - mu) * rsig * gv.w + bv.w, 0.0f);

  if constexpr (!HEAD) {
    ushort4 o;
    o.x = f2bf(y0); o.y = f2bf(y1); o.z = f2bf(y2); o.w = f2bf(y3);
    ((ushort4*)(Y + (size_t)b * HDIM))[tid] = o;
  } else {
    const float4 wv = ((const float4*)Wh)[tid];
    float p = y0 * wv.x + y1 * wv.y + y2 * wv.z + y3 * wv.w;
    #pragma unroll
    for (int off = 32; off; off >>= 1) p += __shfl_xor(p, off);
    if (lane == 0) rp_[wave] = p;
    __syncthreads();
    if (tid < 64) {
      const float qf = rp_[0] + rp_[1] + rp_[2] + rp_[3];
      out[(size_t)b * NQD + tid] = qf + qt[tid];
    }
  }
}

// ---------------- launch ----------------

extern "C" void kernel_launch(void* const* d_in, const int* in_sizes, int n_in,
                              void* d_out, int out_size, void* d_ws, size_t ws_size,
                              hipStream_t stream) {
  (void)in_sizes; (void)n_in; (void)out_size; (void)ws_size;
  const float* state  = (const float*)d_in[0];
  const float* action = (const float*)d_in[1];
  const float* We1 = (const float*)d_in[2];
  const float* be1 = (const float*)d_in[3];
  const float* We2 = (const float*)d_in[4];
  const float* be2 = (const float*)d_in[5];
  const float* Wf1 = (const float*)d_in[6];
  const float* bW1 = (const float*)d_in[7];
  const float* g1  = (const float*)d_in[8];
  const float* bt1 = (const float*)d_in[9];
  const float* Wf2 = (const float*)d_in[10];
  const float* bW2 = (const float*)d_in[11];
  const float* g2  = (const float*)d_in[12];
  const float* bt2 = (const float*)d_in[13];
  const float* Wh  = (const float*)d_in[14];
  const float* bh  = (const float*)d_in[15];
  float* out = (float*)d_out;

  char* ws = (char*)d_ws;
  unsigned short* xb   = (unsigned short*)(ws);               // BATCH*576 bf16
  unsigned short* w1b  = (unsigned short*)(ws + 18874368);    // 2*1024*576 bf16
  unsigned short* w2b  = (unsigned short*)(ws + 21233664);    // 2*1024*1024 bf16
  float*          qtw  = (float*)(ws + 25427968);             // 2*64 f32
  unsigned short* ha   = (unsigned short*)(ws + 25428480);    // BATCH*1024 bf16
  unsigned short* hb   = (unsigned short*)(ws + 58982912);    // BATCH*1024 bf16

  prep<<<2048, 256, 0, stream>>>(state, action, xb, Wf1, w1b, Wf2, w2b);
  qtau_kernel<<<128, 64, 0, stream>>>(We1, be1, We2, be2, Wh, bh, qtw);

  for (int c = 0; c < 2; ++c) {
    gemm_mn<XDIM><<<512, 512, 0, stream>>>(
        xb, w1b + (size_t)c * HDIM * XDIM, bW1 + c * HDIM, ha);
    ln_head<false><<<BATCH, 256, 0, stream>>>(
        ha, g1 + c * HDIM, bt1 + c * HDIM, hb, nullptr, nullptr, nullptr);
    gemm_mn<HDIM><<<512, 512, 0, stream>>>(
        hb, w2b + (size_t)c * HDIM * HDIM, bW2 + c * HDIM, ha);
    ln_head<true><<<BATCH, 256, 0, stream>>>(
        ha, g2 + c * HDIM, bt2 + c * HDIM, nullptr,
        Wh + (size_t)c * (HDIM + QED), qtw + c * 64, out + (size_t)c * BATCH * NQD);
  }
}

// Round 11
// 202.171 us; speedup vs baseline: 1.1527x; 1.0561x over previous
//
#include <hip/hip_runtime.h>
#include <stdint.h>

#define BATCH 16384
#define SDIM 512
#define ADIM 64
#define XDIM 576      // SDIM + ADIM
#define HDIM 1024
#define NQD 64
#define QED 64

typedef __attribute__((ext_vector_type(8))) short short8;
typedef __attribute__((ext_vector_type(4))) float f32x4;

static __device__ inline unsigned short f2bf(float f) {
  unsigned int u = __float_as_uint(f);
  unsigned int r = (u + 0x7fffu + ((u >> 16) & 1u)) >> 16;
  return (unsigned short)r;
}
static __device__ inline float bf2f(unsigned short u) {
  return __uint_as_float(((unsigned int)u) << 16);
}

static __device__ inline void gload_lds16(const void* g, void* l) {
  __builtin_amdgcn_global_load_lds(
      (const __attribute__((address_space(1))) uint32_t*)g,
      (__attribute__((address_space(3))) uint32_t*)l, 16, 0, 0);
}

// ---------------- merged conversion kernel ----------------

__global__ __launch_bounds__(256) void prep(const float* __restrict__ st,
                                            const float* __restrict__ ac,
                                            unsigned short* __restrict__ xb,
                                            const float* __restrict__ w1s,
                                            unsigned short* __restrict__ w1d,
                                            const float* __restrict__ w2s,
                                            unsigned short* __restrict__ w2d) {
  const int nx = BATCH * XDIM / 4;
  const int n1 = 2 * HDIM * XDIM / 4;
  const int n2 = 2 * HDIM * HDIM / 4;
  for (int i = blockIdx.x * blockDim.x + threadIdx.x; i < nx + n1 + n2;
       i += gridDim.x * blockDim.x) {
    float4 v;
    unsigned short* dst;
    int di;
    if (i < nx) {
      const int e = i * 4;
      const int b = e / XDIM;
      const int j = e - b * XDIM;
      if (j < SDIM) v = *(const float4*)(st + (size_t)b * SDIM + j);
      else          v = *(const float4*)(ac + (size_t)b * ADIM + (j - SDIM));
      dst = xb; di = i;
    } else if (i < nx + n1) {
      di = i - nx; v = ((const float4*)w1s)[di]; dst = w1d;
    } else {
      di = i - nx - n1; v = ((const float4*)w2s)[di]; dst = w2d;
    }
    ushort4 o;
    o.x = f2bf(v.x); o.y = f2bf(v.y); o.z = f2bf(v.z); o.w = f2bf(v.w);
    ((ushort4*)dst)[di] = o;
  }
}

// ---------------- tau embedding head contribution (exact fp32) ----------------

__global__ void qtau_kernel(const float* __restrict__ We1, const float* __restrict__ be1,
                            const float* __restrict__ We2, const float* __restrict__ be2,
                            const float* __restrict__ Wh,  const float* __restrict__ bh,
                            float* __restrict__ qtau) {
  const int c = blockIdx.x >> 6;
  const int nq = blockIdx.x & 63;
  const int q = threadIdx.x;  // 64 threads = 1 wave
  const float tau = (float)nq / 64.0f + 0.0078125f;
  float acc = be2[c * 64 + q];
  for (int e = 0; e < 64; ++e) {
    const float t1 = fmaxf(tau * We1[c * 64 + e] + be1[c * 64 + e], 0.0f);
    acc += t1 * We2[(c * 64 + q) * 64 + e];
  }
  float v = acc * Wh[c * (HDIM + QED) + HDIM + q];
  #pragma unroll
  for (int off = 32; off; off >>= 1) v += __shfl_xor(v, off);
  if (q == 0) qtau[c * 64 + nq] = v + bh[c];
}

// ---------------- critic-batched 256x128 bf16 GEMM -------------------------
// Both critics in ONE dispatch (grid 1024). C[c][M,1024] = A[c] * W[c]^T + b[c].
// Inner structure = R8 (best measured): 8 waves (4M x 2N), BK=32, 48 KiB LDS
// double-buffer, both-sides slot swizzle, 3 blocks/CU capacity.
// Block mapping: XCD x = bid&7 owns logical L = x*128 + (bid>>3);
// L = ((m*2 + c)*8 + n) -> the 16 blocks (8n x 2c) sharing an A-panel are
// XCD-co-resident (gemm1: A also shared ACROSS critics -> fetched once).
// NOTE: A and C must NOT alias (R9 bug: in-dispatch cross-block RW race).

template <int K>
__global__ __launch_bounds__(512, 4) void gemm_bc(const unsigned short* __restrict__ Abase,
                                                  size_t aCritStride,
                                                  const unsigned short* __restrict__ Wbase,
                                                  const float* __restrict__ biasBase,
                                                  unsigned short* __restrict__ Cbase) {
  constexpr int NT = K / 32;
  __shared__ unsigned short As[2][256][32];  // 32 KiB
  __shared__ unsigned short Bs[2][128][32];  // 16 KiB

  const int tid  = threadIdx.x;
  const int lane = tid & 63;
  const int wave = tid >> 6;
  const int wm = wave >> 1;   // 0..3 -> rows [wm*64, wm*64+64)
  const int wn = wave & 1;    // 0..1 -> cols [wn*64, wn*64+64)

  const int bid = (int)blockIdx.x;
  const int L = (bid & 7) * 128 + (bid >> 3);
  const int n = L & 7;
  const int cidx = (L >> 3) & 1;
  const int m = L >> 4;
  const int mBase = m * 256;
  const int nBase = n * 128;

  const unsigned short* A = Abase + aCritStride * (size_t)cidx;
  const unsigned short* W = Wbase + (size_t)cidx * HDIM * K;
  const float* bias = biasBase + cidx * HDIM;
  unsigned short* C = Cbase + (size_t)cidx * BATCH * HDIM;

  auto stage = [&](int buf, int kt) {
    #pragma unroll
    for (int i = 0; i < 2; ++i) {
      const int flat = i * 512 + tid;
      const int row  = flat >> 2;
      const int ls   = (flat & 3) ^ ((row >> 1) & 3);
      gload_lds16(A + (size_t)(mBase + row) * K + kt * 32 + ls * 8,
                  &As[buf][0][0] + (size_t)flat * 8);
    }
    {
      const int row = tid >> 2;
      const int ls  = (tid & 3) ^ ((row >> 1) & 3);
      gload_lds16(W + (size_t)(nBase + row) * K + kt * 32 + ls * 8,
                  &Bs[buf][0][0] + (size_t)tid * 8);
    }
  };

  f32x4 acc[4][4];
  #pragma unroll
  for (int fm = 0; fm < 4; ++fm)
    #pragma unroll
    for (int fn = 0; fn < 4; ++fn) {
      f32x4 z = {0.f, 0.f, 0.f, 0.f};
      acc[fm][fn] = z;
    }

  stage(0, 0);
  __syncthreads();

  for (int t = 0; t < NT; ++t) {
    const int buf = t & 1;
    if (t + 1 < NT) stage(buf ^ 1, t + 1);

    short8 af[4], bf[4];
    #pragma unroll
    for (int fm = 0; fm < 4; ++fm) {
      const int r  = wm * 64 + fm * 16 + (lane & 15);
      const int ps = (lane >> 4) ^ ((r >> 1) & 3);
      af[fm] = *(const short8*)&As[buf][r][ps * 8];
    }
    #pragma unroll
    for (int fn = 0; fn < 4; ++fn) {
      const int r  = wn * 64 + fn * 16 + (lane & 15);
      const int ps = (lane >> 4) ^ ((r >> 1) & 3);
      bf[fn] = *(const short8*)&Bs[buf][r][ps * 8];
    }

    __builtin_amdgcn_s_setprio(1);
    #pragma unroll
    for (int fm = 0; fm < 4; ++fm)
      #pragma unroll
      for (int fn = 0; fn < 4; ++fn)
        acc[fm][fn] = __builtin_amdgcn_mfma_f32_16x16x32_bf16(af[fm], bf[fn],
                                                              acc[fm][fn], 0, 0, 0);
    __builtin_amdgcn_s_setprio(0);
    __syncthreads();
  }

  // epilogue: bias add + bf16 round + store
  #pragma unroll
  for (int fm = 0; fm < 4; ++fm) {
    const int r0 = mBase + wm * 64 + fm * 16 + (lane >> 4) * 4;
    #pragma unroll
    for (int fn = 0; fn < 4; ++fn) {
      const int col = nBase + wn * 64 + fn * 16 + (lane & 15);
      const float bv = bias[col];
      #pragma unroll
      for (int j = 0; j < 4; ++j)
        C[(size_t)(r0 + j) * HDIM + col] = f2bf(acc[fm][fn][j] + bv);
    }
  }
}

// ---------------- critic-batched LayerNorm + ReLU (+ head) -----------------
// grid = 2*BATCH blocks; c = blockIdx>>14. Reads X, writes Y (no aliasing).
// HEAD fuses the W_h dot + qtau broadcast -> writes fp32 output directly.

template <bool HEAD>
__global__ __launch_bounds__(256) void ln_bc(const unsigned short* __restrict__ Xb,
                                             const float* __restrict__ gB,
                                             const float* __restrict__ btB,
                                             unsigned short* __restrict__ Yb,
                                             const float* __restrict__ WhB,
                                             const float* __restrict__ qtB,
                                             float* __restrict__ outB) {
  const int gb = blockIdx.x;
  const int c = gb >> 14;                 // BATCH = 2^14
  const int row = gb & (BATCH - 1);
  const unsigned short* X = Xb + ((size_t)c * BATCH + row) * HDIM;
  const float* g   = gB + c * HDIM;
  const float* bta = btB + c * HDIM;

  const int tid = threadIdx.x;
  const int lane = tid & 63;
  const int wave = tid >> 6;
  __shared__ float rs_[4], rq_[4], rp_[4];

  const ushort4 xv = ((const ushort4*)X)[tid];
  const float x0 = bf2f(xv.x), x1 = bf2f(xv.y), x2 = bf2f(xv.z), x3 = bf2f(xv.w);
  float s = x0 + x1 + x2 + x3;
  float q = x0 * x0 + x1 * x1 + x2 * x2 + x3 * x3;
  #pragma unroll
  for (int off = 32; off; off >>= 1) {
    s += __shfl_xor(s, off);
    q += __shfl_xor(q, off);
  }
  if (lane == 0) { rs_[wave] = s; rq_[wave] = q; }
  __syncthreads();
  s = rs_[0] + rs_[1] + rs_[2] + rs_[3];
  q = rq_[0] + rq_[1] + rq_[2] + rq_[3];
  const float mu = s * (1.0f / 1024.0f);
  const float var = q * (1.0f / 1024.0f) - mu * mu;
  const float rsig = rsqrtf(var + 1e-5f);

  const float4 gv = ((const float4*)g)[tid];
  const float4 bv = ((const float4*)bta)[tid];
  const float y0 = fmaxf((x0 - mu) * rsig * gv.x + bv.x, 0.0f);
  const float y1 = fmaxf((x1 - mu) * rsig * gv.y + bv.y, 0.0f);
  const float y2 = fmaxf((x2 - mu) * rsig * gv.z + bv.z, 0.0f);
  const float y3 = fmaxf((x3 - mu) * rsig * gv.w + bv.w, 0.0f);

  if constexpr (!HEAD) {
    ushort4 o;
    o.x = f2bf(y0); o.y = f2bf(y1); o.z = f2bf(y2); o.w = f2bf(y3);
    ((ushort4*)(Yb + ((size_t)c * BATCH + row) * HDIM))[tid] = o;
  } else {
    const float* Wh = WhB + c * (HDIM + QED);
    const float4 wv = ((const float4*)Wh)[tid];
    float p = y0 * wv.x + y1 * wv.y + y2 * wv.z + y3 * wv.w;
    #pragma unroll
    for (int off = 32; off; off >>= 1) p += __shfl_xor(p, off);
    if (lane == 0) rp_[wave] = p;
    __syncthreads();
    if (tid < 64) {
      const float qf = rp_[0] + rp_[1] + rp_[2] + rp_[3];
      outB[((size_t)c * BATCH + row) * NQD + tid] = qf + qtB[c * 64 + tid];
    }
  }
}

// ---------------- launch ----------------

extern "C" void kernel_launch(void* const* d_in, const int* in_sizes, int n_in,
                              void* d_out, int out_size, void* d_ws, size_t ws_size,
                              hipStream_t stream) {
  (void)in_sizes; (void)n_in; (void)out_size; (void)ws_size;
  const float* state  = (const float*)d_in[0];
  const float* action = (const float*)d_in[1];
  const float* We1 = (const float*)d_in[2];
  const float* be1 = (const float*)d_in[3];
  const float* We2 = (const float*)d_in[4];
  const float* be2 = (const float*)d_in[5];
  const float* Wf1 = (const float*)d_in[6];
  const float* bW1 = (const float*)d_in[7];
  const float* g1  = (const float*)d_in[8];
  const float* bt1 = (const float*)d_in[9];
  const float* Wf2 = (const float*)d_in[10];
  const float* bW2 = (const float*)d_in[11];
  const float* g2  = (const float*)d_in[12];
  const float* bt2 = (const float*)d_in[13];
  const float* Wh  = (const float*)d_in[14];
  const float* bh  = (const float*)d_in[15];
  float* out = (float*)d_out;

  char* ws = (char*)d_ws;
  unsigned short* xb   = (unsigned short*)(ws);               // BATCH*576 bf16   (18,874,368 B)
  unsigned short* w1b  = (unsigned short*)(ws + 18874368);    // 2*1024*576 bf16  (2,359,296 B)
  unsigned short* w2b  = (unsigned short*)(ws + 21233664);    // 2*1024*1024 bf16 (4,194,304 B)
  float*          qtw  = (float*)(ws + 25427968);             // 2*64 f32 (512 B)
  unsigned short* ha   = (unsigned short*)(ws + 25428480);    // 2*BATCH*1024 bf16 (67,108,864 B) -> ends 92,537,344
  unsigned short* hb   = (unsigned short*)(ws + 92537344);    // 2*BATCH*1024 bf16 (67,108,864 B) -> ends 159,646,208
  // total ws use: 159,646,208 B (ha/hb disjoint — R10 bug was a 512 B overlap)

  prep<<<2048, 256, 0, stream>>>(state, action, xb, Wf1, w1b, Wf2, w2b);
  qtau_kernel<<<128, 64, 0, stream>>>(We1, be1, We2, be2, Wh, bh, qtw);

  // layer 1, both critics (A shared across critics): ha = x @ W1^T + b1
  gemm_bc<XDIM><<<1024, 512, 0, stream>>>(xb, 0, w1b, bW1, ha);
  ln_bc<false><<<2 * BATCH, 256, 0, stream>>>(ha, g1, bt1, hb, nullptr, nullptr, nullptr);
  // layer 2, both critics: ha = hb @ W2^T + b2 ; then LN+head -> out
  gemm_bc<HDIM><<<1024, 512, 0, stream>>>(hb, (size_t)BATCH * HDIM, w2b, bW2, ha);
  ln_bc<true><<<2 * BATCH, 256, 0, stream>>>(ha, g2, bt2, nullptr, Wh, qtw, out);
}

// Round 12
// 198.238 us; speedup vs baseline: 1.1755x; 1.0198x over previous
//
#include <hip/hip_runtime.h>
#include <stdint.h>

#define BATCH 16384
#define SDIM 512
#define ADIM 64
#define XDIM 576      // SDIM + ADIM
#define HDIM 1024
#define NQD 64
#define QED 64

typedef __attribute__((ext_vector_type(8))) short short8;
typedef __attribute__((ext_vector_type(4))) float f32x4;

static __device__ inline unsigned short f2bf(float f) {
  unsigned int u = __float_as_uint(f);
  unsigned int r = (u + 0x7fffu + ((u >> 16) & 1u)) >> 16;
  return (unsigned short)r;
}
static __device__ inline float bf2f(unsigned short u) {
  return __uint_as_float(((unsigned int)u) << 16);
}

static __device__ inline void gload_lds16(const void* g, void* l) {
  __builtin_amdgcn_global_load_lds(
      (const __attribute__((address_space(1))) uint32_t*)g,
      (__attribute__((address_space(3))) uint32_t*)l, 16, 0, 0);
}

// ---------------- merged conversion kernel ----------------

__global__ __launch_bounds__(256) void prep(const float* __restrict__ st,
                                            const float* __restrict__ ac,
                                            unsigned short* __restrict__ xb,
                                            const float* __restrict__ w1s,
                                            unsigned short* __restrict__ w1d,
                                            const float* __restrict__ w2s,
                                            unsigned short* __restrict__ w2d) {
  const int nx = BATCH * XDIM / 4;
  const int n1 = 2 * HDIM * XDIM / 4;
  const int n2 = 2 * HDIM * HDIM / 4;
  for (int i = blockIdx.x * blockDim.x + threadIdx.x; i < nx + n1 + n2;
       i += gridDim.x * blockDim.x) {
    float4 v;
    unsigned short* dst;
    int di;
    if (i < nx) {
      const int e = i * 4;
      const int b = e / XDIM;
      const int j = e - b * XDIM;
      if (j < SDIM) v = *(const float4*)(st + (size_t)b * SDIM + j);
      else          v = *(const float4*)(ac + (size_t)b * ADIM + (j - SDIM));
      dst = xb; di = i;
    } else if (i < nx + n1) {
      di = i - nx; v = ((const float4*)w1s)[di]; dst = w1d;
    } else {
      di = i - nx - n1; v = ((const float4*)w2s)[di]; dst = w2d;
    }
    ushort4 o;
    o.x = f2bf(v.x); o.y = f2bf(v.y); o.z = f2bf(v.z); o.w = f2bf(v.w);
    ((ushort4*)dst)[di] = o;
  }
}

// ---------------- tau embedding head contribution (exact fp32) ----------------

__global__ void qtau_kernel(const float* __restrict__ We1, const float* __restrict__ be1,
                            const float* __restrict__ We2, const float* __restrict__ be2,
                            const float* __restrict__ Wh,  const float* __restrict__ bh,
                            float* __restrict__ qtau) {
  const int c = blockIdx.x >> 6;
  const int nq = blockIdx.x & 63;
  const int q = threadIdx.x;  // 64 threads = 1 wave
  const float tau = (float)nq / 64.0f + 0.0078125f;
  float acc = be2[c * 64 + q];
  for (int e = 0; e < 64; ++e) {
    const float t1 = fmaxf(tau * We1[c * 64 + e] + be1[c * 64 + e], 0.0f);
    acc += t1 * We2[(c * 64 + q) * 64 + e];
  }
  float v = acc * Wh[c * (HDIM + QED) + HDIM + q];
  #pragma unroll
  for (int off = 32; off; off >>= 1) v += __shfl_xor(v, off);
  if (q == 0) qtau[c * 64 + nq] = v + bh[c];
}

// ---------------- critic-batched 256x128 bf16 GEMM -------------------------
// Both critics in ONE dispatch (grid 1024). C[c][M,1024] = A[c] * W[c]^T + b[c].
// K-loop = R8/R11 (proven): 8 waves (4M x 2N), BK=32, 48 KiB LDS dbuf,
// both-sides slot swizzle. NEW: packed epilogue — per-wave LDS transpose
// (wave-private 32x144B patch in the As/Bs pool, one barrier after K-loop),
// stores as dwordx4 with 8 lanes covering one full 128B line (was 64 scalar
// 2B stores/thread -> 8 packed 16B stores/thread, full-line coalesced).

template <int K>
__global__ __launch_bounds__(512, 4) void gemm_bc(const unsigned short* __restrict__ Abase,
                                                  size_t aCritStride,
                                                  const unsigned short* __restrict__ Wbase,
                                                  const float* __restrict__ biasBase,
                                                  unsigned short* __restrict__ Cbase) {
  constexpr int NT = K / 32;
  __shared__ unsigned short As[2][256][32];  // 32 KiB
  __shared__ unsigned short Bs[2][128][32];  // 16 KiB  (48 KiB pool, reused by epilogue)

  const int tid  = threadIdx.x;
  const int lane = tid & 63;
  const int wave = tid >> 6;
  const int wm = wave >> 1;   // 0..3 -> rows [wm*64, wm*64+64)
  const int wn = wave & 1;    // 0..1 -> cols [wn*64, wn*64+64)

  const int bid = (int)blockIdx.x;
  const int L = (bid & 7) * 128 + (bid >> 3);
  const int n = L & 7;
  const int cidx = (L >> 3) & 1;
  const int m = L >> 4;
  const int mBase = m * 256;
  const int nBase = n * 128;

  const unsigned short* A = Abase + aCritStride * (size_t)cidx;
  const unsigned short* W = Wbase + (size_t)cidx * HDIM * K;
  const float* bias = biasBase + cidx * HDIM;
  unsigned short* C = Cbase + (size_t)cidx * BATCH * HDIM;

  auto stage = [&](int buf, int kt) {
    #pragma unroll
    for (int i = 0; i < 2; ++i) {
      const int flat = i * 512 + tid;
      const int row  = flat >> 2;
      const int ls   = (flat & 3) ^ ((row >> 1) & 3);
      gload_lds16(A + (size_t)(mBase + row) * K + kt * 32 + ls * 8,
                  &As[buf][0][0] + (size_t)flat * 8);
    }
    {
      const int row = tid >> 2;
      const int ls  = (tid & 3) ^ ((row >> 1) & 3);
      gload_lds16(W + (size_t)(nBase + row) * K + kt * 32 + ls * 8,
                  &Bs[buf][0][0] + (size_t)tid * 8);
    }
  };

  f32x4 acc[4][4];
  #pragma unroll
  for (int fm = 0; fm < 4; ++fm)
    #pragma unroll
    for (int fn = 0; fn < 4; ++fn) {
      f32x4 z = {0.f, 0.f, 0.f, 0.f};
      acc[fm][fn] = z;
    }

  stage(0, 0);
  __syncthreads();

  for (int t = 0; t < NT; ++t) {
    const int buf = t & 1;
    if (t + 1 < NT) stage(buf ^ 1, t + 1);

    short8 af[4], bf[4];
    #pragma unroll
    for (int fm = 0; fm < 4; ++fm) {
      const int r  = wm * 64 + fm * 16 + (lane & 15);
      const int ps = (lane >> 4) ^ ((r >> 1) & 3);
      af[fm] = *(const short8*)&As[buf][r][ps * 8];
    }
    #pragma unroll
    for (int fn = 0; fn < 4; ++fn) {
      const int r  = wn * 64 + fn * 16 + (lane & 15);
      const int ps = (lane >> 4) ^ ((r >> 1) & 3);
      bf[fn] = *(const short8*)&Bs[buf][r][ps * 8];
    }

    __builtin_amdgcn_s_setprio(1);
    #pragma unroll
    for (int fm = 0; fm < 4; ++fm)
      #pragma unroll
      for (int fn = 0; fn < 4; ++fn)
        acc[fm][fn] = __builtin_amdgcn_mfma_f32_16x16x32_bf16(af[fm], bf[fn],
                                                              acc[fm][fn], 0, 0, 0);
    __builtin_amdgcn_s_setprio(0);
    __syncthreads();
  }

  // ---- packed epilogue: LDS transpose -> full-128B-line dwordx4 stores ----
  __syncthreads();  // all waves done reading As/Bs before patch overwrite
  // wave-private patch: 32 rows x 72 shorts (144B pad -> conflict-free reads)
  unsigned short* patch = ((unsigned short*)&As[0][0][0]) + wave * 2304;  // 4608 B/wave, 36.9 KB total

  float bcol[4];
  #pragma unroll
  for (int fn = 0; fn < 4; ++fn)
    bcol[fn] = bias[nBase + wn * 64 + fn * 16 + (lane & 15)];

  const int cBase = nBase + wn * 64;

  #pragma unroll
  for (int p = 0; p < 2; ++p) {
    // scatter 32 rows of this wave's C half-tile into the patch (bf16)
    #pragma unroll
    for (int f2 = 0; f2 < 2; ++f2) {
      const int fm = p * 2 + f2;
      #pragma unroll
      for (int fn = 0; fn < 4; ++fn) {
        const int rl = f2 * 16 + (lane >> 4) * 4;
        const int cl = fn * 16 + (lane & 15);
        #pragma unroll
        for (int j = 0; j < 4; ++j)
          patch[(rl + j) * 72 + cl] = f2bf(acc[fm][fn][j] + bcol[fn]);
      }
    }
    // gather packed: 8 lanes cover one full 128B C line; 4 insts x 8 rows
    #pragma unroll
    for (int k = 0; k < 4; ++k) {
      const int rl = k * 8 + (lane >> 3);
      const short8 v = *(const short8*)&patch[rl * 72 + (lane & 7) * 8];
      const int rowg = mBase + wm * 64 + p * 32 + rl;
      *(short8*)(C + (size_t)rowg * HDIM + cBase + (lane & 7) * 8) = v;
    }
  }
}

// ---------------- critic-batched LayerNorm + ReLU (+ head) -----------------

template <bool HEAD>
__global__ __launch_bounds__(256) void ln_bc(const unsigned short* __restrict__ Xb,
                                             const float* __restrict__ gB,
                                             const float* __restrict__ btB,
                                             unsigned short* __restrict__ Yb,
                                             const float* __restrict__ WhB,
                                             const float* __restrict__ qtB,
                                             float* __restrict__ outB) {
  const int gb = blockIdx.x;
  const int c = gb >> 14;                 // BATCH = 2^14
  const int row = gb & (BATCH - 1);
  const unsigned short* X = Xb + ((size_t)c * BATCH + row) * HDIM;
  const float* g   = gB + c * HDIM;
  const float* bta = btB + c * HDIM;

  const int tid = threadIdx.x;
  const int lane = tid & 63;
  const int wave = tid >> 6;
  __shared__ float rs_[4], rq_[4], rp_[4];

  const ushort4 xv = ((const ushort4*)X)[tid];
  const float x0 = bf2f(xv.x), x1 = bf2f(xv.y), x2 = bf2f(xv.z), x3 = bf2f(xv.w);
  float s = x0 + x1 + x2 + x3;
  float q = x0 * x0 + x1 * x1 + x2 * x2 + x3 * x3;
  #pragma unroll
  for (int off = 32; off; off >>= 1) {
    s += __shfl_xor(s, off);
    q += __shfl_xor(q, off);
  }
  if (lane == 0) { rs_[wave] = s; rq_[wave] = q; }
  __syncthreads();
  s = rs_[0] + rs_[1] + rs_[2] + rs_[3];
  q = rq_[0] + rq_[1] + rq_[2] + rq_[3];
  const float mu = s * (1.0f / 1024.0f);
  const float var = q * (1.0f / 1024.0f) - mu * mu;
  const float rsig = rsqrtf(var + 1e-5f);

  const float4 gv = ((const float4*)g)[tid];
  const float4 bv = ((const float4*)bta)[tid];
  const float y0 = fmaxf((x0 - mu) * rsig * gv.x + bv.x, 0.0f);
  const float y1 = fmaxf((x1 - mu) * rsig * gv.y + bv.y, 0.0f);
  const float y2 = fmaxf((x2 - mu) * rsig * gv.z + bv.z, 0.0f);
  const float y3 = fmaxf((x3 - mu) * rsig * gv.w + bv.w, 0.0f);

  if constexpr (!HEAD) {
    ushort4 o;
    o.x = f2bf(y0); o.y = f2bf(y1); o.z = f2bf(y2); o.w = f2bf(y3);
    ((ushort4*)(Yb + ((size_t)c * BATCH + row) * HDIM))[tid] = o;
  } else {
    const float* Wh = WhB + c * (HDIM + QED);
    const float4 wv = ((const float4*)Wh)[tid];
    float p = y0 * wv.x + y1 * wv.y + y2 * wv.z + y3 * wv.w;
    #pragma unroll
    for (int off = 32; off; off >>= 1) p += __shfl_xor(p, off);
    if (lane == 0) rp_[wave] = p;
    __syncthreads();
    if (tid < 64) {
      const float qf = rp_[0] + rp_[1] + rp_[2] + rp_[3];
      outB[((size_t)c * BATCH + row) * NQD + tid] = qf + qtB[c * 64 + tid];
    }
  }
}

// ---------------- launch ----------------

extern "C" void kernel_launch(void* const* d_in, const int* in_sizes, int n_in,
                              void* d_out, int out_size, void* d_ws, size_t ws_size,
                              hipStream_t stream) {
  (void)in_sizes; (void)n_in; (void)out_size; (void)ws_size;
  const float* state  = (const float*)d_in[0];
  const float* action = (const float*)d_in[1];
  const float* We1 = (const float*)d_in[2];
  const float* be1 = (const float*)d_in[3];
  const float* We2 = (const float*)d_in[4];
  const float* be2 = (const float*)d_in[5];
  const float* Wf1 = (const float*)d_in[6];
  const float* bW1 = (const float*)d_in[7];
  const float* g1  = (const float*)d_in[8];
  const float* bt1 = (const float*)d_in[9];
  const float* Wf2 = (const float*)d_in[10];
  const float* bW2 = (const float*)d_in[11];
  const float* g2  = (const float*)d_in[12];
  const float* bt2 = (const float*)d_in[13];
  const float* Wh  = (const float*)d_in[14];
  const float* bh  = (const float*)d_in[15];
  float* out = (float*)d_out;

  char* ws = (char*)d_ws;
  unsigned short* xb   = (unsigned short*)(ws);               // BATCH*576 bf16   (18,874,368 B)
  unsigned short* w1b  = (unsigned short*)(ws + 18874368);    // 2*1024*576 bf16  (2,359,296 B)
  unsigned short* w2b  = (unsigned short*)(ws + 21233664);    // 2*1024*1024 bf16 (4,194,304 B)
  float*          qtw  = (float*)(ws + 25427968);             // 2*64 f32 (512 B)
  unsigned short* ha   = (unsigned short*)(ws + 25428480);    // 2*BATCH*1024 bf16 -> ends 92,537,344
  unsigned short* hb   = (unsigned short*)(ws + 92537344);    // 2*BATCH*1024 bf16 -> ends 159,646,208

  prep<<<2048, 256, 0, stream>>>(state, action, xb, Wf1, w1b, Wf2, w2b);
  qtau_kernel<<<128, 64, 0, stream>>>(We1, be1, We2, be2, Wh, bh, qtw);

  // layer 1, both critics (A shared across critics): ha = x @ W1^T + b1
  gemm_bc<XDIM><<<1024, 512, 0, stream>>>(xb, 0, w1b, bW1, ha);
  ln_bc<false><<<2 * BATCH, 256, 0, stream>>>(ha, g1, bt1, hb, nullptr, nullptr, nullptr);
  // layer 2, both critics: ha = hb @ W2^T + b2 ; then LN+head -> out
  gemm_bc<HDIM><<<1024, 512, 0, stream>>>(hb, (size_t)BATCH * HDIM, w2b, bW2, ha);
  ln_bc<true><<<2 * BATCH, 256, 0, stream>>>(ha, g2, bt2, nullptr, Wh, qtw, out);
}